// Round 1
// baseline (2416.598 us; speedup 1.0000x reference)
//
#include <hip/hip_runtime.h>
#include <stdint.h>

#define N_KEYS 200000
#define N_Q    1024
#define DIM    128
#define KNN    50
#define DELTA  1e-3f

// main GEMM tiling
#define QT      64
#define KT      2048
#define KC      64
#define QTILES  (N_Q / QT)                      // 16
#define KSLICES ((N_KEYS + KT - 1) / KT)        // 98

// sampling for threshold
#define SAMPLES        2048
#define SAMPLE_STRIDE  97
#define SAMPLE_RANK    30

#define CAP_MAX 6144

// ---------------------------------------------------------------- zero cnt
__global__ void zero_cnt_kernel(unsigned int* cnt) {
    int i = blockIdx.x * 256 + threadIdx.x;
    if (i < N_Q) cnt[i] = 0u;
}

// ---------------------------------------------------------------- row sums of squares
__global__ void sq_kernel(const float* __restrict__ qry, const float* __restrict__ keys,
                          float* __restrict__ ksq, float* __restrict__ qsq) {
    int sub = threadIdx.x & 15;          // 16 lanes per row
    int grp = threadIdx.x >> 4;          // 16 rows per block-iter
    const long total = (long)N_KEYS + N_Q;
    for (long row = (long)blockIdx.x * 16 + grp; row < total; row += (long)gridDim.x * 16) {
        const float* src = (row < N_KEYS) ? (keys + row * DIM)
                                          : (qry + (row - N_KEYS) * DIM);
        float4 a = ((const float4*)src)[sub * 2];
        float4 b = ((const float4*)src)[sub * 2 + 1];
        float acc = a.x * a.x;
        acc = fmaf(a.y, a.y, acc); acc = fmaf(a.z, a.z, acc); acc = fmaf(a.w, a.w, acc);
        acc = fmaf(b.x, b.x, acc); acc = fmaf(b.y, b.y, acc);
        acc = fmaf(b.z, b.z, acc); acc = fmaf(b.w, b.w, acc);
        #pragma unroll
        for (int m = 1; m < 16; m <<= 1) acc += __shfl_xor(acc, m);
        if (sub == 0) {
            if (row < N_KEYS) ksq[row] = acc;
            else              qsq[row - N_KEYS] = acc;
        }
    }
}

// ---------------------------------------------------------------- per-query sample threshold
__global__ void tau_kernel(const float* __restrict__ qry, const float* __restrict__ keys,
                           float* __restrict__ tau0) {
    __shared__ float Qs[DIM];
    __shared__ float Ds[SAMPLES];
    __shared__ unsigned int cnt_s;
    const int q = blockIdx.x, tid = threadIdx.x;
    if (tid < 32) ((float4*)Qs)[tid] = ((const float4*)(qry + (size_t)q * DIM))[tid];
    __syncthreads();

    const int sub = tid & 15, grp = tid >> 4;    // 16 groups of 16 lanes
    const float4 qa = ((float4*)Qs)[sub * 2];
    const float4 qb = ((float4*)Qs)[sub * 2 + 1];
    for (int s = grp; s < SAMPLES; s += 16) {
        const int kidx = s * SAMPLE_STRIDE;
        const float4* kr = (const float4*)(keys + (size_t)kidx * DIM);
        float4 a = kr[sub * 2], b = kr[sub * 2 + 1];
        float t, acc;
        t = qa.x - a.x; acc = t * t;
        t = qa.y - a.y; acc = fmaf(t, t, acc);
        t = qa.z - a.z; acc = fmaf(t, t, acc);
        t = qa.w - a.w; acc = fmaf(t, t, acc);
        t = qb.x - b.x; acc = fmaf(t, t, acc);
        t = qb.y - b.y; acc = fmaf(t, t, acc);
        t = qb.z - b.z; acc = fmaf(t, t, acc);
        t = qb.w - b.w; acc = fmaf(t, t, acc);
        #pragma unroll
        for (int m = 1; m < 16; m <<= 1) acc += __shfl_xor(acc, m);
        if (sub == 0) Ds[s] = acc;
    }
    __syncthreads();

    // radix-select: largest v with countLess(v) < SAMPLE_RANK (positive floats == uint order)
    unsigned int v = 0;
    for (int bit = 30; bit >= 0; bit--) {
        const unsigned int tbits = v | (1u << bit);
        const float tf = __uint_as_float(tbits);
        if (tid == 0) cnt_s = 0;
        __syncthreads();
        unsigned int lc = 0;
        for (int i = tid; i < SAMPLES; i += 256) lc += (Ds[i] < tf) ? 1u : 0u;
        #pragma unroll
        for (int off = 32; off; off >>= 1) lc += __shfl_down(lc, off);
        if ((tid & 63) == 0) atomicAdd(&cnt_s, lc);
        __syncthreads();
        if (cnt_s < SAMPLE_RANK) v = tbits;
        __syncthreads();
    }
    if (tid == 0) tau0[q] = __uint_as_float(v);
}

// ---------------------------------------------------------------- fused distance GEMM + filter
__global__ __launch_bounds__(128)
void gemm_filter_kernel(const float* __restrict__ qry, const float* __restrict__ keys,
                        const float* __restrict__ ksq_g, const float* __restrict__ qsq_g,
                        const float* __restrict__ tau0_g, unsigned int* __restrict__ cnt,
                        float2* __restrict__ cand, int cap) {
    __shared__ float Qlds[DIM][QT];   // transposed: [dim][query]  32 KB
    __shared__ float Klds[DIM][KC];   // transposed: [dim][key]    32 KB
    const int tid = threadIdx.x;
    const int qtile = blockIdx.x & (QTILES - 1);
    const int kslice = blockIdx.x >> 4;
    const int qbase = qtile * QT;
    const int kbase_s = kslice * KT;

    // stage Q tile (once)
    {
        const int qq = tid & 63, half = tid >> 6;
        const float* src = qry + (size_t)(qbase + qq) * DIM;
        #pragma unroll
        for (int s = 0; s < 16; s++) {
            const int d0 = half * 64 + s * 4;
            float4 vv = *(const float4*)(src + d0);
            Qlds[d0 + 0][qq] = vv.x; Qlds[d0 + 1][qq] = vv.y;
            Qlds[d0 + 2][qq] = vv.z; Qlds[d0 + 3][qq] = vv.w;
        }
    }

    const int tq = tid & 7;        // 8 groups of 8 queries
    const int tk = tid >> 3;       // 16 groups of 4 keys
    const int tq8 = tq * 8, tk4 = tk * 4;

    float qsq8[8], thr8[8]; int qidx8[8];
    #pragma unroll
    for (int i = 0; i < 8; i++) {
        const int q = qbase + tq8 + i;
        qidx8[i] = q;
        qsq8[i] = qsq_g[q];
        thr8[i] = tau0_g[q] - qsq8[i];   // test: ksq - 2*dot < thr  <=>  dist < tau0
    }

    const int nkeys = (N_KEYS - kbase_s < KT) ? (N_KEYS - kbase_s) : KT;
    for (int c0 = 0; c0 < nkeys; c0 += KC) {
        const int kb = kbase_s + c0;
        __syncthreads();
        {   // stage K chunk (transposed)
            const int kk = tid & 63, half = tid >> 6;
            const int krow = kb + kk;
            const float* src = keys + (size_t)krow * DIM;
            const bool val = (krow < N_KEYS);
            #pragma unroll
            for (int s = 0; s < 16; s++) {
                const int d0 = half * 64 + s * 4;
                float4 vv = val ? *(const float4*)(src + d0) : make_float4(0.f, 0.f, 0.f, 0.f);
                Klds[d0 + 0][kk] = vv.x; Klds[d0 + 1][kk] = vv.y;
                Klds[d0 + 2][kk] = vv.z; Klds[d0 + 3][kk] = vv.w;
            }
        }
        __syncthreads();

        float ksq4[4]; int kidx4[4];
        #pragma unroll
        for (int j = 0; j < 4; j++) {
            const int ki = kb + tk4 + j;
            kidx4[j] = ki;
            ksq4[j] = (ki < N_KEYS) ? ksq_g[ki] : 3.0e38f;  // huge => never passes filter
        }

        float acc[8][4];
        #pragma unroll
        for (int i = 0; i < 8; i++)
            #pragma unroll
            for (int j = 0; j < 4; j++) acc[i][j] = 0.f;

        #pragma unroll 8
        for (int d = 0; d < DIM; d++) {
            const float4 a = *(const float4*)&Qlds[d][tq8];
            const float4 b = *(const float4*)&Qlds[d][tq8 + 4];
            const float4 kv = *(const float4*)&Klds[d][tk4];
            const float qv[8] = {a.x, a.y, a.z, a.w, b.x, b.y, b.z, b.w};
            const float kj[4] = {kv.x, kv.y, kv.z, kv.w};
            #pragma unroll
            for (int i = 0; i < 8; i++)
                #pragma unroll
                for (int j = 0; j < 4; j++)
                    acc[i][j] = fmaf(qv[i], kj[j], acc[i][j]);
        }

        #pragma unroll
        for (int i = 0; i < 8; i++) {
            #pragma unroll
            for (int j = 0; j < 4; j++) {
                const float m = fmaf(-2.f, acc[i][j], ksq4[j]);
                if (m < thr8[i]) {
                    const float dist = qsq8[i] + m;
                    const unsigned p = atomicAdd(&cnt[qidx8[i]], 1u);
                    if ((int)p < cap)
                        cand[(size_t)qidx8[i] * cap + p] =
                            make_float2(dist, __uint_as_float((unsigned)kidx4[j]));
                }
            }
        }
    }
}

// ---------------------------------------------------------------- exact top-50 + IDW
__global__ void select_idw_kernel(const float2* __restrict__ cand, const unsigned int* __restrict__ cnt,
                                  const float* __restrict__ values, float* __restrict__ out, int cap) {
    __shared__ unsigned long long keyarr[CAP_MAX];
    __shared__ unsigned long long sel[KNN];
    __shared__ float vv[KNN];
    __shared__ unsigned int cnt_s, ns;
    const int q = blockIdx.x, tid = threadIdx.x;
    const int c = min((int)cnt[q], cap);

    for (int i = tid; i < c; i += 256) {
        const float2 f = cand[(size_t)q * cap + i];
        const unsigned int db = __float_as_uint(f.x);
        const unsigned int ix = __float_as_uint(f.y);
        keyarr[i] = ((unsigned long long)db << 32) | ix;
    }
    __syncthreads();

    const int ksel = min(KNN, c);
    if (ksel == 0) { if (tid == 0) out[q] = 0.f; return; }

    // binary search on combined (dist_bits, idx) key for the ksel-th smallest
    unsigned long long lo = 0ull, hi = ~0ull;
    while (hi - lo > 1ull) {
        const unsigned long long mid = lo + ((hi - lo) >> 1);
        if (tid == 0) cnt_s = 0;
        __syncthreads();
        unsigned int lc = 0;
        for (int i = tid; i < c; i += 256) lc += (keyarr[i] < mid) ? 1u : 0u;
        #pragma unroll
        for (int off = 32; off; off >>= 1) lc += __shfl_down(lc, off);
        if ((tid & 63) == 0) atomicAdd(&cnt_s, lc);
        __syncthreads();
        if (cnt_s >= (unsigned)ksel) hi = mid; else lo = mid;
        __syncthreads();
    }
    const unsigned long long thr = lo;   // exactly ksel keys are <= thr (keys unique)

    if (tid == 0) ns = 0;
    __syncthreads();
    for (int i = tid; i < c; i += 256) {
        if (keyarr[i] <= thr) {
            const unsigned p = atomicAdd(&ns, 1u);
            if (p < (unsigned)KNN) sel[p] = keyarr[i];
        }
    }
    __syncthreads();

    if (tid == 0) {  // deterministic order: insertion sort ascending (dist, idx)
        for (int a = 1; a < ksel; a++) {
            const unsigned long long x = sel[a];
            int b = a - 1;
            while (b >= 0 && sel[b] > x) { sel[b + 1] = sel[b]; b--; }
            sel[b + 1] = x;
        }
    }
    __syncthreads();
    if (tid < ksel) vv[tid] = values[(unsigned)(sel[tid] & 0xFFFFFFFFull)];
    __syncthreads();

    if (tid == 0) {
        const float d0 = fmaxf(__uint_as_float((unsigned)(sel[0] >> 32)), 0.f);
        float res;
        if (d0 == 0.f) {
            res = vv[0];
        } else {
            float S = 0.f;
            for (int i = 0; i < ksel; i++) {
                const float di = fmaxf(__uint_as_float((unsigned)(sel[i] >> 32)), 0.f);
                S += 1.f / (di + DELTA);
            }
            float o = 0.f;
            for (int i = 0; i < ksel; i++) {
                const float di = fmaxf(__uint_as_float((unsigned)(sel[i] >> 32)), 0.f);
                const float w = 1.f / (di + DELTA);
                o += (w / S) * vv[i];
            }
            res = o;
        }
        out[q] = res;
    }
}

// ---------------------------------------------------------------- launcher
extern "C" void kernel_launch(void* const* d_in, const int* in_sizes, int n_in,
                              void* d_out, int out_size, void* d_ws, size_t ws_size,
                              hipStream_t stream) {
    const float* qry    = (const float*)d_in[0];   // [1024,128]
    const float* keys   = (const float*)d_in[1];   // [200000,128]
    const float* values = (const float*)d_in[2];   // [200000,1]
    float* out = (float*)d_out;

    char* ws = (char*)d_ws;
    float*        ksq  = (float*)(ws);             // 800000 B
    float*        qsq  = (float*)(ws + 800000);    // 4096 B
    float*        tau0 = (float*)(ws + 804096);    // 4096 B
    unsigned int* cnt  = (unsigned int*)(ws + 808192); // 4096 B
    float2*       cand = (float2*)(ws + 812288);

    long avail = (ws_size > 812288) ? (long)((ws_size - 812288) / ((size_t)N_Q * 8)) : 1;
    int cap = (avail < (long)CAP_MAX) ? (int)avail : CAP_MAX;
    if (cap < 1) cap = 1;

    hipLaunchKernelGGL(zero_cnt_kernel, dim3(4), dim3(256), 0, stream, cnt);
    hipLaunchKernelGGL(sq_kernel, dim3(1024), dim3(256), 0, stream, qry, keys, ksq, qsq);
    hipLaunchKernelGGL(tau_kernel, dim3(N_Q), dim3(256), 0, stream, qry, keys, tau0);
    hipLaunchKernelGGL(gemm_filter_kernel, dim3(QTILES * KSLICES), dim3(128), 0, stream,
                       qry, keys, ksq, qsq, tau0, cnt, cand, cap);
    hipLaunchKernelGGL(select_idw_kernel, dim3(N_Q), dim3(256), 0, stream,
                       cand, cnt, values, out, cap);
}

// Round 2
// 1242.015 us; speedup vs baseline: 1.9457x; 1.9457x over previous
//
#include <hip/hip_runtime.h>
#include <stdint.h>

#define N_KEYS 200000
#define N_Q    1024
#define DIM    128
#define KNN    50
#define DELTA  1e-3f

// ---------------- old fp32 path tiling (fallback) ----------------
#define QT      64
#define KT      2048
#define KC      64
#define QTILES  (N_Q / QT)                      // 16
#define KSLICES ((N_KEYS + KT - 1) / KT)        // 98

// ---------------- sampling for threshold ----------------
#define SAMPLES        2048
#define SAMPLE_STRIDE  97

#define CAP_MAX 6144        // fallback path
#define CAP_NEW 3072        // mfma path

// ---------------- mfma path geometry ----------------
#define NKP     200064      // 1563 * 128 (padded keys)
#define KTILES2 1563
#define QTILES2 8
#define MARGIN  0.05f

typedef __attribute__((ext_vector_type(8))) short bf16x8;
typedef __attribute__((ext_vector_type(4))) float f32x4;
typedef unsigned long long ull;

// ================================================================ helpers
__device__ inline unsigned bf16_rn_bits(float x) {
    unsigned u = __float_as_uint(x);
    return (u + 0x7FFFu + ((u >> 16) & 1u)) >> 16;
}
__device__ inline float bf16_to_f32(unsigned h) { return __uint_as_float(h << 16); }

#define GLD16(gsrc, ldst) __builtin_amdgcn_global_load_lds( \
    (const __attribute__((address_space(1))) unsigned int*)(gsrc), \
    (__attribute__((address_space(3))) unsigned int*)(ldst), 16, 0, 0)

// ================================================================ zero cnt
__global__ void zero_cnt_kernel(unsigned int* cnt) {
    int i = blockIdx.x * 256 + threadIdx.x;
    if (i < N_Q) cnt[i] = 0u;
}

// ================================================================ prep: ksq/qsq + bf16 hi/lo split
__global__ void prep_kernel(const float* __restrict__ qry, const float* __restrict__ keys,
                            ushort* __restrict__ Khi, ushort* __restrict__ Klo,
                            ushort* __restrict__ Qhi, ushort* __restrict__ Qlo,
                            float* __restrict__ ksq, float* __restrict__ qsq) {
    const int sub = threadIdx.x & 15;        // 16 lanes per row
    const int grp = threadIdx.x >> 4;        // 16 rows per block
    const long total = (long)NKP + N_Q;
    const long row = (long)blockIdx.x * 16 + grp;
    if (row >= total) return;
    const bool isq = (row >= NKP);

    float4 a, b;
    if (!isq) {
        if (row < N_KEYS) {
            const float4* src = (const float4*)(keys + row * DIM);
            a = src[sub * 2]; b = src[sub * 2 + 1];
        } else {
            a = make_float4(0.f, 0.f, 0.f, 0.f); b = a;
        }
    } else {
        const float4* src = (const float4*)(qry + (row - NKP) * DIM);
        a = src[sub * 2]; b = src[sub * 2 + 1];
    }

    // sum of squares -- identical op order to the round-1 sq_kernel
    float acc = a.x * a.x;
    acc = fmaf(a.y, a.y, acc); acc = fmaf(a.z, a.z, acc); acc = fmaf(a.w, a.w, acc);
    acc = fmaf(b.x, b.x, acc); acc = fmaf(b.y, b.y, acc);
    acc = fmaf(b.z, b.z, acc); acc = fmaf(b.w, b.w, acc);
    #pragma unroll
    for (int m = 1; m < 16; m <<= 1) acc += __shfl_xor(acc, m);

    // bf16 hi/lo split
    const float v[8] = {a.x, a.y, a.z, a.w, b.x, b.y, b.z, b.w};
    unsigned h[8], l[8];
    #pragma unroll
    for (int j = 0; j < 8; j++) {
        h[j] = bf16_rn_bits(v[j]);
        l[j] = bf16_rn_bits(v[j] - bf16_to_f32(h[j]));
    }
    uint4 hv, lv;
    hv.x = h[0] | (h[1] << 16); hv.y = h[2] | (h[3] << 16);
    hv.z = h[4] | (h[5] << 16); hv.w = h[6] | (h[7] << 16);
    lv.x = l[0] | (l[1] << 16); lv.y = l[2] | (l[3] << 16);
    lv.z = l[4] | (l[5] << 16); lv.w = l[6] | (l[7] << 16);

    if (!isq) {
        *(uint4*)(Khi + (size_t)row * DIM + sub * 8) = hv;
        *(uint4*)(Klo + (size_t)row * DIM + sub * 8) = lv;
        if (sub == 0) ksq[row] = (row < N_KEYS) ? acc : 3.0e38f;
    } else {
        const long qr = row - NKP;
        *(uint4*)(Qhi + (size_t)qr * DIM + sub * 8) = hv;
        *(uint4*)(Qlo + (size_t)qr * DIM + sub * 8) = lv;
        if (sub == 0) qsq[qr] = acc;
    }
}

// ================================================================ per-query sample threshold
__global__ void tau_kernel(const float* __restrict__ qry, const float* __restrict__ keys,
                           float* __restrict__ tau0, int rank) {
    __shared__ float Qs[DIM];
    __shared__ float Ds[SAMPLES];
    __shared__ unsigned int cnt_s;
    const int q = blockIdx.x, tid = threadIdx.x;
    if (tid < 32) ((float4*)Qs)[tid] = ((const float4*)(qry + (size_t)q * DIM))[tid];
    __syncthreads();

    const int sub = tid & 15, grp = tid >> 4;
    const float4 qa = ((float4*)Qs)[sub * 2];
    const float4 qb = ((float4*)Qs)[sub * 2 + 1];
    for (int s = grp; s < SAMPLES; s += 16) {
        const int kidx = s * SAMPLE_STRIDE;
        const float4* kr = (const float4*)(keys + (size_t)kidx * DIM);
        float4 a = kr[sub * 2], b = kr[sub * 2 + 1];
        float t, acc;
        t = qa.x - a.x; acc = t * t;
        t = qa.y - a.y; acc = fmaf(t, t, acc);
        t = qa.z - a.z; acc = fmaf(t, t, acc);
        t = qa.w - a.w; acc = fmaf(t, t, acc);
        t = qb.x - b.x; acc = fmaf(t, t, acc);
        t = qb.y - b.y; acc = fmaf(t, t, acc);
        t = qb.z - b.z; acc = fmaf(t, t, acc);
        t = qb.w - b.w; acc = fmaf(t, t, acc);
        #pragma unroll
        for (int m = 1; m < 16; m <<= 1) acc += __shfl_xor(acc, m);
        if (sub == 0) Ds[s] = acc;
    }
    __syncthreads();

    unsigned int v = 0;
    for (int bit = 30; bit >= 0; bit--) {
        const unsigned int tbits = v | (1u << bit);
        const float tf = __uint_as_float(tbits);
        if (tid == 0) cnt_s = 0;
        __syncthreads();
        unsigned int lc = 0;
        for (int i = tid; i < SAMPLES; i += 256) lc += (Ds[i] < tf) ? 1u : 0u;
        #pragma unroll
        for (int off = 32; off; off >>= 1) lc += __shfl_down(lc, off);
        if ((tid & 63) == 0) atomicAdd(&cnt_s, lc);
        __syncthreads();
        if (cnt_s < (unsigned)rank) v = tbits;
        __syncthreads();
    }
    if (tid == 0) tau0[q] = __uint_as_float(v);
}

// ================================================================ MFMA bf16-split distance GEMM + filter
// C[q][k] = dot(Q[q],K[k]) via Qh*Kh + Qh*Kl + Ql*Kh, K_eff = 384, 12 K-steps of 32.
__global__ __launch_bounds__(256)
void mfma_filter_kernel(const ushort* __restrict__ Qhi, const ushort* __restrict__ Qlo,
                        const ushort* __restrict__ Khi, const ushort* __restrict__ Klo,
                        const float* __restrict__ ksq_g, const float* __restrict__ qsq_g,
                        const float* __restrict__ tau_g,
                        unsigned int* __restrict__ cnt, float2* __restrict__ cand, int cap) {
    __shared__ ushort Alds[2][128 * 32];
    __shared__ ushort Blds[2][128 * 32];
    __shared__ float qsq_s[128], thr_s[128], ksq_s[128];

    const int tid = threadIdx.x;
    const int qt = blockIdx.x / KTILES2;
    const int kt = blockIdx.x - qt * KTILES2;
    const int qbase = qt * 128, kbase = kt * 128;

    if (tid < 128) {
        const float qs = qsq_g[qbase + tid];
        qsq_s[tid] = qs;
        thr_s[tid] = tau_g[qbase + tid] - qs;
        ksq_s[tid] = ksq_g[kbase + tid];
    }

    const int lane = tid & 63;
    const int wave = tid >> 6;
    const int wr = wave >> 1, wc = wave & 1;

    // staging geometry: wave-load li covers rows [li*16, li*16+16), lane -> row li*16+(lane>>2), col (lane&3)*8
    const int srow = lane >> 2;
    const int scol = (lane & 3) * 8;
    const size_t aoff0 = (size_t)(qbase + wave * 16 + srow) * DIM + scol;
    const size_t aoff1 = aoff0 + (size_t)64 * DIM;
    const size_t boff0 = (size_t)(kbase + wave * 16 + srow) * DIM + scol;
    const size_t boff1 = boff0 + (size_t)64 * DIM;

    f32x4 acc[4][4];
    #pragma unroll
    for (int i = 0; i < 4; i++)
        #pragma unroll
        for (int j = 0; j < 4; j++) acc[i][j] = (f32x4){0.f, 0.f, 0.f, 0.f};

    // prologue: stage step 0 (seg 0: Qhi x Khi, kcol 0) into buf 0
    GLD16(Qhi + aoff0, &Alds[0][wave * 512]);
    GLD16(Qhi + aoff1, &Alds[0][2048 + wave * 512]);
    GLD16(Khi + boff0, &Blds[0][wave * 512]);
    GLD16(Khi + boff1, &Blds[0][2048 + wave * 512]);

    // fragment read offsets (ushort units), frag f adds f*512
    const int a_rd = (wr * 64 + (lane & 15)) * 32 + (lane >> 4) * 8;
    const int b_rd = (wc * 64 + (lane & 15)) * 32 + (lane >> 4) * 8;

    #pragma unroll
    for (int t = 0; t < 12; ++t) {
        const int buf = t & 1;
        __syncthreads();
        if (t < 11) {
            const int t1 = t + 1, seg = t1 >> 2, kcol = (t1 & 3) * 32;
            const ushort* As = (seg == 2) ? Qlo : Qhi;
            const ushort* Bs = (seg == 1) ? Klo : Khi;
            const int nb = t1 & 1;
            GLD16(As + aoff0 + kcol, &Alds[nb][wave * 512]);
            GLD16(As + aoff1 + kcol, &Alds[nb][2048 + wave * 512]);
            GLD16(Bs + boff0 + kcol, &Blds[nb][wave * 512]);
            GLD16(Bs + boff1 + kcol, &Blds[nb][2048 + wave * 512]);
        }
        bf16x8 af[4], bfr[4];
        #pragma unroll
        for (int f = 0; f < 4; ++f) {
            af[f]  = *(const bf16x8*)&Alds[buf][a_rd + f * 512];
            bfr[f] = *(const bf16x8*)&Blds[buf][b_rd + f * 512];
        }
        #pragma unroll
        for (int i = 0; i < 4; ++i)
            #pragma unroll
            for (int j = 0; j < 4; ++j)
                acc[i][j] = __builtin_amdgcn_mfma_f32_16x16x32_bf16(af[i], bfr[j], acc[i][j], 0, 0, 0);
    }

    // epilogue: dist = qsq + (ksq - 2*dot); append candidates below tau
    const int col  = lane & 15;
    const int rowb = (lane >> 4) * 4;
    #pragma unroll
    for (int i = 0; i < 4; ++i) {
        #pragma unroll
        for (int j = 0; j < 4; ++j) {
            #pragma unroll
            for (int r = 0; r < 4; ++r) {
                const int ql = wr * 64 + i * 16 + rowb + r;
                const int kl = wc * 64 + j * 16 + col;
                const float mm = fmaf(-2.f, acc[i][j][r], ksq_s[kl]);
                if (mm < thr_s[ql]) {
                    const float dist = qsq_s[ql] + mm;
                    const int qg = qbase + ql;
                    const unsigned p = atomicAdd(&cnt[qg], 1u);
                    if ((int)p < cap)
                        cand[(size_t)qg * cap + p] =
                            make_float2(dist, __uint_as_float((unsigned)(kbase + kl)));
                }
            }
        }
    }
}

// ================================================================ select: approx top-50 window -> exact fp32 recompute -> IDW
__global__ void select_exact_kernel(const float2* __restrict__ cand, const unsigned int* __restrict__ cnt,
                                    const float* __restrict__ keys, const float* __restrict__ qry,
                                    const float* __restrict__ ksq_g, const float* __restrict__ qsq_g,
                                    const float* __restrict__ values, float* __restrict__ out, int cap) {
    __shared__ float Qs[DIM];
    __shared__ ull keyarr[CAP_NEW];
    __shared__ int keep[256];
    __shared__ ull ex[256];
    __shared__ ull sel[KNN];
    __shared__ float vv[KNN];
    __shared__ unsigned int cnt_s, ns;
    const int q = blockIdx.x, tid = threadIdx.x;

    if (tid < 32) ((float4*)Qs)[tid] = ((const float4*)(qry + (size_t)q * DIM))[tid];
    const int c = min((int)cnt[q], cap);
    for (int i = tid; i < c; i += 256) {
        const float2 f = cand[(size_t)q * cap + i];
        keyarr[i] = ((ull)__float_as_uint(f.x) << 32) | __float_as_uint(f.y);
    }
    __syncthreads();

    const int ksel = min(KNN, c);
    if (ksel == 0) { if (tid == 0) out[q] = 0.f; return; }

    // 1) ksel-th smallest approx (64-bit key) via binary search
    ull lo = 0ull, hi = ~0ull;
    while (hi - lo > 1ull) {
        const ull mid = lo + ((hi - lo) >> 1);
        if (tid == 0) cnt_s = 0;
        __syncthreads();
        unsigned int lc = 0;
        for (int i = tid; i < c; i += 256) lc += (keyarr[i] < mid) ? 1u : 0u;
        #pragma unroll
        for (int off = 32; off; off >>= 1) lc += __shfl_down(lc, off);
        if ((tid & 63) == 0) atomicAdd(&cnt_s, lc);
        __syncthreads();
        if (cnt_s >= (unsigned)ksel) hi = mid; else lo = mid;
        __syncthreads();
    }
    const float a50 = __uint_as_float((unsigned)(lo >> 32));
    const unsigned cutb = __float_as_uint(a50 + MARGIN);

    // 2) keep approx <= a50 + margin
    if (tid == 0) ns = 0;
    __syncthreads();
    for (int i = tid; i < c; i += 256) {
        if ((unsigned)(keyarr[i] >> 32) <= cutb) {
            const unsigned p = atomicAdd(&ns, 1u);
            if (p < 256u) keep[p] = (int)(keyarr[i] & 0xFFFFFFFFull);
        }
    }
    __syncthreads();
    const int m = min((int)ns, 256);

    // 3) exact fp32 distance (round-1 arithmetic: sequential fmaf dot)
    const float qsq = qsq_g[q];
    for (int j = tid; j < m; j += 256) {
        const int kidx = keep[j];
        const float* kr = keys + (size_t)kidx * DIM;
        float dot = 0.f;
        for (int d = 0; d < DIM; d++) dot = fmaf(Qs[d], kr[d], dot);
        const float mm = fmaf(-2.f, dot, ksq_g[kidx]);
        const float dist = qsq + mm;
        ex[j] = ((ull)__float_as_uint(dist) << 32) | (unsigned)kidx;
    }
    __syncthreads();

    const int kex = min(KNN, m);
    // 4) exact kex-th smallest among kept
    lo = 0ull; hi = ~0ull;
    while (hi - lo > 1ull) {
        const ull mid = lo + ((hi - lo) >> 1);
        if (tid == 0) cnt_s = 0;
        __syncthreads();
        unsigned int lc = 0;
        for (int i = tid; i < m; i += 256) lc += (ex[i] < mid) ? 1u : 0u;
        #pragma unroll
        for (int off = 32; off; off >>= 1) lc += __shfl_down(lc, off);
        if ((tid & 63) == 0) atomicAdd(&cnt_s, lc);
        __syncthreads();
        if (cnt_s >= (unsigned)kex) hi = mid; else lo = mid;
        __syncthreads();
    }
    const ull thr2 = lo;

    if (tid == 0) ns = 0;
    __syncthreads();
    for (int i = tid; i < m; i += 256) {
        if (ex[i] <= thr2) {
            const unsigned p = atomicAdd(&ns, 1u);
            if (p < (unsigned)KNN) sel[p] = ex[i];
        }
    }
    __syncthreads();

    if (tid == 0) {
        for (int a = 1; a < kex; a++) {
            const ull x = sel[a];
            int b = a - 1;
            while (b >= 0 && sel[b] > x) { sel[b + 1] = sel[b]; b--; }
            sel[b + 1] = x;
        }
    }
    __syncthreads();
    if (tid < kex) vv[tid] = values[(unsigned)(sel[tid] & 0xFFFFFFFFull)];
    __syncthreads();

    if (tid == 0) {
        const float d0 = fmaxf(__uint_as_float((unsigned)(sel[0] >> 32)), 0.f);
        float res;
        if (d0 == 0.f) {
            res = vv[0];
        } else {
            float S = 0.f;
            for (int i = 0; i < kex; i++) {
                const float di = fmaxf(__uint_as_float((unsigned)(sel[i] >> 32)), 0.f);
                S += 1.f / (di + DELTA);
            }
            float o = 0.f;
            for (int i = 0; i < kex; i++) {
                const float di = fmaxf(__uint_as_float((unsigned)(sel[i] >> 32)), 0.f);
                const float w = 1.f / (di + DELTA);
                o += (w / S) * vv[i];
            }
            res = o;
        }
        out[q] = res;
    }
}

// ================================================================ FALLBACK (round-1 fp32 path, proven)
__global__ void sq_kernel(const float* __restrict__ qry, const float* __restrict__ keys,
                          float* __restrict__ ksq, float* __restrict__ qsq) {
    int sub = threadIdx.x & 15;
    int grp = threadIdx.x >> 4;
    const long total = (long)N_KEYS + N_Q;
    for (long row = (long)blockIdx.x * 16 + grp; row < total; row += (long)gridDim.x * 16) {
        const float* src = (row < N_KEYS) ? (keys + row * DIM)
                                          : (qry + (row - N_KEYS) * DIM);
        float4 a = ((const float4*)src)[sub * 2];
        float4 b = ((const float4*)src)[sub * 2 + 1];
        float acc = a.x * a.x;
        acc = fmaf(a.y, a.y, acc); acc = fmaf(a.z, a.z, acc); acc = fmaf(a.w, a.w, acc);
        acc = fmaf(b.x, b.x, acc); acc = fmaf(b.y, b.y, acc);
        acc = fmaf(b.z, b.z, acc); acc = fmaf(b.w, b.w, acc);
        #pragma unroll
        for (int m = 1; m < 16; m <<= 1) acc += __shfl_xor(acc, m);
        if (sub == 0) {
            if (row < N_KEYS) ksq[row] = acc;
            else              qsq[row - N_KEYS] = acc;
        }
    }
}

__global__ __launch_bounds__(128)
void gemm_filter_kernel(const float* __restrict__ qry, const float* __restrict__ keys,
                        const float* __restrict__ ksq_g, const float* __restrict__ qsq_g,
                        const float* __restrict__ tau0_g, unsigned int* __restrict__ cnt,
                        float2* __restrict__ cand, int cap) {
    __shared__ float Qlds[DIM][QT];
    __shared__ float Klds[DIM][KC];
    const int tid = threadIdx.x;
    const int qtile = blockIdx.x & (QTILES - 1);
    const int kslice = blockIdx.x >> 4;
    const int qbase = qtile * QT;
    const int kbase_s = kslice * KT;

    {
        const int qq = tid & 63, half = tid >> 6;
        const float* src = qry + (size_t)(qbase + qq) * DIM;
        #pragma unroll
        for (int s = 0; s < 16; s++) {
            const int d0 = half * 64 + s * 4;
            float4 vvv = *(const float4*)(src + d0);
            Qlds[d0 + 0][qq] = vvv.x; Qlds[d0 + 1][qq] = vvv.y;
            Qlds[d0 + 2][qq] = vvv.z; Qlds[d0 + 3][qq] = vvv.w;
        }
    }

    const int tq = tid & 7;
    const int tk = tid >> 3;
    const int tq8 = tq * 8, tk4 = tk * 4;

    float qsq8[8], thr8[8]; int qidx8[8];
    #pragma unroll
    for (int i = 0; i < 8; i++) {
        const int q = qbase + tq8 + i;
        qidx8[i] = q;
        qsq8[i] = qsq_g[q];
        thr8[i] = tau0_g[q] - qsq8[i];
    }

    const int nkeys = (N_KEYS - kbase_s < KT) ? (N_KEYS - kbase_s) : KT;
    for (int c0 = 0; c0 < nkeys; c0 += KC) {
        const int kb = kbase_s + c0;
        __syncthreads();
        {
            const int kk = tid & 63, half = tid >> 6;
            const int krow = kb + kk;
            const float* src = keys + (size_t)krow * DIM;
            const bool val = (krow < N_KEYS);
            #pragma unroll
            for (int s = 0; s < 16; s++) {
                const int d0 = half * 64 + s * 4;
                float4 vvv = val ? *(const float4*)(src + d0) : make_float4(0.f, 0.f, 0.f, 0.f);
                Klds[d0 + 0][kk] = vvv.x; Klds[d0 + 1][kk] = vvv.y;
                Klds[d0 + 2][kk] = vvv.z; Klds[d0 + 3][kk] = vvv.w;
            }
        }
        __syncthreads();

        float ksq4[4]; int kidx4[4];
        #pragma unroll
        for (int j = 0; j < 4; j++) {
            const int ki = kb + tk4 + j;
            kidx4[j] = ki;
            ksq4[j] = (ki < N_KEYS) ? ksq_g[ki] : 3.0e38f;
        }

        float acc[8][4];
        #pragma unroll
        for (int i = 0; i < 8; i++)
            #pragma unroll
            for (int j = 0; j < 4; j++) acc[i][j] = 0.f;

        #pragma unroll 8
        for (int d = 0; d < DIM; d++) {
            const float4 a = *(const float4*)&Qlds[d][tq8];
            const float4 b = *(const float4*)&Qlds[d][tq8 + 4];
            const float4 kv = *(const float4*)&Klds[d][tk4];
            const float qv[8] = {a.x, a.y, a.z, a.w, b.x, b.y, b.z, b.w};
            const float kj[4] = {kv.x, kv.y, kv.z, kv.w};
            #pragma unroll
            for (int i = 0; i < 8; i++)
                #pragma unroll
                for (int j = 0; j < 4; j++)
                    acc[i][j] = fmaf(qv[i], kj[j], acc[i][j]);
        }

        #pragma unroll
        for (int i = 0; i < 8; i++) {
            #pragma unroll
            for (int j = 0; j < 4; j++) {
                const float m = fmaf(-2.f, acc[i][j], ksq4[j]);
                if (m < thr8[i]) {
                    const float dist = qsq8[i] + m;
                    const unsigned p = atomicAdd(&cnt[qidx8[i]], 1u);
                    if ((int)p < cap)
                        cand[(size_t)qidx8[i] * cap + p] =
                            make_float2(dist, __uint_as_float((unsigned)kidx4[j]));
                }
            }
        }
    }
}

__global__ void select_idw_kernel(const float2* __restrict__ cand, const unsigned int* __restrict__ cnt,
                                  const float* __restrict__ values, float* __restrict__ out, int cap) {
    __shared__ unsigned long long keyarr[CAP_MAX];
    __shared__ unsigned long long sel[KNN];
    __shared__ float vv[KNN];
    __shared__ unsigned int cnt_s, ns;
    const int q = blockIdx.x, tid = threadIdx.x;
    const int c = min((int)cnt[q], cap);

    for (int i = tid; i < c; i += 256) {
        const float2 f = cand[(size_t)q * cap + i];
        keyarr[i] = ((unsigned long long)__float_as_uint(f.x) << 32) | __float_as_uint(f.y);
    }
    __syncthreads();

    const int ksel = min(KNN, c);
    if (ksel == 0) { if (tid == 0) out[q] = 0.f; return; }

    unsigned long long lo = 0ull, hi = ~0ull;
    while (hi - lo > 1ull) {
        const unsigned long long mid = lo + ((hi - lo) >> 1);
        if (tid == 0) cnt_s = 0;
        __syncthreads();
        unsigned int lc = 0;
        for (int i = tid; i < c; i += 256) lc += (keyarr[i] < mid) ? 1u : 0u;
        #pragma unroll
        for (int off = 32; off; off >>= 1) lc += __shfl_down(lc, off);
        if ((tid & 63) == 0) atomicAdd(&cnt_s, lc);
        __syncthreads();
        if (cnt_s >= (unsigned)ksel) hi = mid; else lo = mid;
        __syncthreads();
    }
    const unsigned long long thr = lo;

    if (tid == 0) ns = 0;
    __syncthreads();
    for (int i = tid; i < c; i += 256) {
        if (keyarr[i] <= thr) {
            const unsigned p = atomicAdd(&ns, 1u);
            if (p < (unsigned)KNN) sel[p] = keyarr[i];
        }
    }
    __syncthreads();

    if (tid == 0) {
        for (int a = 1; a < ksel; a++) {
            const unsigned long long x = sel[a];
            int b = a - 1;
            while (b >= 0 && sel[b] > x) { sel[b + 1] = sel[b]; b--; }
            sel[b + 1] = x;
        }
    }
    __syncthreads();
    if (tid < ksel) vv[tid] = values[(unsigned)(sel[tid] & 0xFFFFFFFFull)];
    __syncthreads();

    if (tid == 0) {
        const float d0 = fmaxf(__uint_as_float((unsigned)(sel[0] >> 32)), 0.f);
        float res;
        if (d0 == 0.f) {
            res = vv[0];
        } else {
            float S = 0.f;
            for (int i = 0; i < ksel; i++) {
                const float di = fmaxf(__uint_as_float((unsigned)(sel[i] >> 32)), 0.f);
                S += 1.f / (di + DELTA);
            }
            float o = 0.f;
            for (int i = 0; i < ksel; i++) {
                const float di = fmaxf(__uint_as_float((unsigned)(sel[i] >> 32)), 0.f);
                const float w = 1.f / (di + DELTA);
                o += (w / S) * vv[i];
            }
            res = o;
        }
        out[q] = res;
    }
}

// ================================================================ launcher
extern "C" void kernel_launch(void* const* d_in, const int* in_sizes, int n_in,
                              void* d_out, int out_size, void* d_ws, size_t ws_size,
                              hipStream_t stream) {
    const float* qry    = (const float*)d_in[0];   // [1024,128]
    const float* keys   = (const float*)d_in[1];   // [200000,128]
    const float* values = (const float*)d_in[2];   // [200000,1]
    float* out = (float*)d_out;
    char* ws = (char*)d_ws;

    // new-path workspace layout (all 512B-aligned)
    const size_t KHI_OFF  = 0;
    const size_t KLO_OFF  = KHI_OFF + (size_t)NKP * DIM * 2;     // 51,216,384
    const size_t QHI_OFF  = KLO_OFF + (size_t)NKP * DIM * 2;
    const size_t QLO_OFF  = QHI_OFF + (size_t)N_Q * DIM * 2;
    const size_t KSQ_OFF  = QLO_OFF + (size_t)N_Q * DIM * 2;
    const size_t QSQ_OFF  = KSQ_OFF + (size_t)NKP * 4;           // 800,256 (512-mult)
    const size_t TAU_OFF  = QSQ_OFF + 4096;
    const size_t CNT_OFF  = TAU_OFF + 4096;
    const size_t CAND_OFF = CNT_OFF + 4096;
    const size_t NEED     = CAND_OFF + (size_t)N_Q * CAP_NEW * 8;

    if (ws_size >= NEED) {
        ushort* Khi = (ushort*)(ws + KHI_OFF);
        ushort* Klo = (ushort*)(ws + KLO_OFF);
        ushort* Qhi = (ushort*)(ws + QHI_OFF);
        ushort* Qlo = (ushort*)(ws + QLO_OFF);
        float*  ksq = (float*)(ws + KSQ_OFF);
        float*  qsq = (float*)(ws + QSQ_OFF);
        float*  tau = (float*)(ws + TAU_OFF);
        unsigned int* cnt = (unsigned int*)(ws + CNT_OFF);
        float2* cand = (float2*)(ws + CAND_OFF);

        hipLaunchKernelGGL(zero_cnt_kernel, dim3(4), dim3(256), 0, stream, cnt);
        hipLaunchKernelGGL(prep_kernel, dim3((NKP + N_Q) / 16), dim3(256), 0, stream,
                           qry, keys, Khi, Klo, Qhi, Qlo, ksq, qsq);
        hipLaunchKernelGGL(tau_kernel, dim3(N_Q), dim3(256), 0, stream, qry, keys, tau, 8);
        hipLaunchKernelGGL(mfma_filter_kernel, dim3(QTILES2 * KTILES2), dim3(256), 0, stream,
                           Qhi, Qlo, Khi, Klo, ksq, qsq, tau, cnt, cand, CAP_NEW);
        hipLaunchKernelGGL(select_exact_kernel, dim3(N_Q), dim3(256), 0, stream,
                           cand, cnt, keys, qry, ksq, qsq, values, out, CAP_NEW);
    } else {
        float*        ksq  = (float*)(ws);
        float*        qsq  = (float*)(ws + 800000);
        float*        tau0 = (float*)(ws + 804096);
        unsigned int* cnt  = (unsigned int*)(ws + 808192);
        float2*       cand = (float2*)(ws + 812288);

        long avail = (ws_size > 812288) ? (long)((ws_size - 812288) / ((size_t)N_Q * 8)) : 1;
        int cap = (avail < (long)CAP_MAX) ? (int)avail : CAP_MAX;
        if (cap < 1) cap = 1;

        hipLaunchKernelGGL(zero_cnt_kernel, dim3(4), dim3(256), 0, stream, cnt);
        hipLaunchKernelGGL(sq_kernel, dim3(1024), dim3(256), 0, stream, qry, keys, ksq, qsq);
        hipLaunchKernelGGL(tau_kernel, dim3(N_Q), dim3(256), 0, stream, qry, keys, tau0, 30);
        hipLaunchKernelGGL(gemm_filter_kernel, dim3(QTILES * KSLICES), dim3(128), 0, stream,
                           qry, keys, ksq, qsq, tau0, cnt, cand, cap);
        hipLaunchKernelGGL(select_idw_kernel, dim3(N_Q), dim3(256), 0, stream,
                           cand, cnt, values, out, cap);
    }
}

// Round 3
// 558.528 us; speedup vs baseline: 4.3267x; 2.2237x over previous
//
#include <hip/hip_runtime.h>
#include <stdint.h>

#define N_KEYS 200000
#define N_Q    1024
#define DIM    128
#define KNN    50
#define DELTA  1e-3f

#define NKP     200064                 // 1563 * 128 padded keys
#define KTILES2 1563
#define GRID_FILTER (1568 * 8)         // y: 8 qt x 196 ktHigh, x: kt%8 (XCD)
#define SAMPLES        2048
#define SAMPLE_STRIDE  97
#define SAMPLE_RANK    8
#define CAP_NEW 3072
#define MARGIN  0.25f                  // exact-recompute window slack (fp16 err <<)
#define TSLACK  0.25f                  // tau filter slack for fp16 approx error

typedef __attribute__((ext_vector_type(8))) _Float16 f16x8;
typedef __attribute__((ext_vector_type(4))) float f32x4;
typedef unsigned long long ull;

#define GLD16(gsrc, ldst) __builtin_amdgcn_global_load_lds( \
    (const __attribute__((address_space(1))) unsigned int*)(gsrc), \
    (__attribute__((address_space(3))) unsigned int*)(ldst), 16, 0, 0)

// ================================================================ zero cnt
__global__ void zero_cnt_kernel(unsigned int* cnt) {
    int i = blockIdx.x * 256 + threadIdx.x;
    if (i < N_Q) cnt[i] = 0u;
}

// ================================================================ prep: fp32 -> f16 fragment-tiled + row sq-sums
// Output layout (f16): chunk (grp, s) at offset (grp*4+s)*512 + lane*8,
// holding M[grp*16 + (lane&15)][s*32 + (lane>>4)*8 .. +8).
// One wave per 16-row group; all reads/writes coalesced.
__global__ void prep_kernel(const float* __restrict__ qry, const float* __restrict__ keys,
                            ushort* __restrict__ Kf, ushort* __restrict__ Qf,
                            float* __restrict__ ksq, float* __restrict__ qsq) {
    const int wave = threadIdx.x >> 6, lane = threadIdx.x & 63;
    const long NKG = NKP / 16;              // 12504
    const long NQG = N_Q / 16;              // 64
    const long grp = (long)blockIdx.x * 4 + wave;
    if (grp >= NKG + NQG) return;
    const bool isq = (grp >= NKG);
    const long lgrp = isq ? (grp - NKG) : grp;
    const long row = lgrp * 16 + (lane & 15);
    const int  hi  = lane >> 4;
    const bool valid = isq || (row < N_KEYS);
    const float* src = isq ? (qry + row * DIM) : (keys + (valid ? row * DIM : 0));

    float ss = 0.f;
    uint4 hv[4];
    #pragma unroll
    for (int s = 0; s < 4; ++s) {
        float4 a, b;
        if (valid) {
            const float4* p = (const float4*)(src + s * 32 + hi * 8);
            a = p[0]; b = p[1];
        } else {
            a = make_float4(0.f, 0.f, 0.f, 0.f); b = a;
        }
        ss = fmaf(a.x, a.x, ss); ss = fmaf(a.y, a.y, ss);
        ss = fmaf(a.z, a.z, ss); ss = fmaf(a.w, a.w, ss);
        ss = fmaf(b.x, b.x, ss); ss = fmaf(b.y, b.y, ss);
        ss = fmaf(b.z, b.z, ss); ss = fmaf(b.w, b.w, ss);
        const float v[8] = {a.x, a.y, a.z, a.w, b.x, b.y, b.z, b.w};
        unsigned h[8];
        #pragma unroll
        for (int j = 0; j < 8; ++j) {
            _Float16 t = (_Float16)v[j];
            h[j] = (unsigned)__builtin_bit_cast(unsigned short, t);
        }
        hv[s].x = h[0] | (h[1] << 16); hv[s].y = h[2] | (h[3] << 16);
        hv[s].z = h[4] | (h[5] << 16); hv[s].w = h[6] | (h[7] << 16);
    }
    // row sum of squares: lanes {r, r+16, r+32, r+48} hold the 4 quarter-sums
    ss += __shfl_xor(ss, 16);
    ss += __shfl_xor(ss, 32);

    ushort* dst = isq ? Qf : Kf;
    #pragma unroll
    for (int s = 0; s < 4; ++s)
        *(uint4*)(dst + (size_t)(lgrp * 4 + s) * 512 + lane * 8) = hv[s];

    if (lane < 16) {
        if (isq) qsq[row] = ss;
        else if (row < NKP) ksq[row] = valid ? ss : 3.0e38f;
    }
}

// ================================================================ per-query sampled threshold (exact fp32)
__global__ void tau_kernel(const float* __restrict__ qry, const float* __restrict__ keys,
                           float* __restrict__ tau0, int rank) {
    __shared__ float Qs[DIM];
    __shared__ float Ds[SAMPLES];
    __shared__ unsigned int cnt_s;
    const int q = blockIdx.x, tid = threadIdx.x;
    if (tid < 32) ((float4*)Qs)[tid] = ((const float4*)(qry + (size_t)q * DIM))[tid];
    __syncthreads();

    const int sub = tid & 15, grp = tid >> 4;
    const float4 qa = ((float4*)Qs)[sub * 2];
    const float4 qb = ((float4*)Qs)[sub * 2 + 1];
    for (int s = grp; s < SAMPLES; s += 16) {
        const int kidx = s * SAMPLE_STRIDE;
        const float4* kr = (const float4*)(keys + (size_t)kidx * DIM);
        float4 a = kr[sub * 2], b = kr[sub * 2 + 1];
        float t, acc;
        t = qa.x - a.x; acc = t * t;
        t = qa.y - a.y; acc = fmaf(t, t, acc);
        t = qa.z - a.z; acc = fmaf(t, t, acc);
        t = qa.w - a.w; acc = fmaf(t, t, acc);
        t = qb.x - b.x; acc = fmaf(t, t, acc);
        t = qb.y - b.y; acc = fmaf(t, t, acc);
        t = qb.z - b.z; acc = fmaf(t, t, acc);
        t = qb.w - b.w; acc = fmaf(t, t, acc);
        #pragma unroll
        for (int m = 1; m < 16; m <<= 1) acc += __shfl_xor(acc, m);
        if (sub == 0) Ds[s] = acc;
    }
    __syncthreads();

    unsigned int v = 0;
    for (int bit = 30; bit >= 0; bit--) {
        const unsigned int tbits = v | (1u << bit);
        const float tf = __uint_as_float(tbits);
        if (tid == 0) cnt_s = 0;
        __syncthreads();
        unsigned int lc = 0;
        for (int i = tid; i < SAMPLES; i += 256) lc += (Ds[i] < tf) ? 1u : 0u;
        #pragma unroll
        for (int off = 32; off; off >>= 1) lc += __shfl_down(lc, off);
        if ((tid & 63) == 0) atomicAdd(&cnt_s, lc);
        __syncthreads();
        if (cnt_s < (unsigned)rank) v = tbits;
        __syncthreads();
    }
    if (tid == 0) tau0[q] = __uint_as_float(v);
}

// ================================================================ f16 MFMA distance GEMM + filter
// 128q x 128k per block; fragment-ordered tiles; 1 barrier; 0 bank conflicts.
__global__ __launch_bounds__(256)
void mfma_filter_kernel(const ushort* __restrict__ Qf, const ushort* __restrict__ Kf,
                        const float* __restrict__ ksq_g, const float* __restrict__ qsq_g,
                        const float* __restrict__ tau_g,
                        unsigned int* __restrict__ cnt, float2* __restrict__ cand, int cap) {
    __shared__ ushort Alds[32 * 512];   // 32 KB  Q tile (fragment order)
    __shared__ ushort Blds[32 * 512];   // 32 KB  K tile
    __shared__ float qsq_s[128], thr_s[128], ksq_s[128];

    // XCD-aware decode: same-kt blocks (8 qt) share wg%8 -> same XCD, adjacent dispatch
    const int wg = blockIdx.x;
    const int x = wg & 7, y = wg >> 3;
    const int qt = y & 7;
    const int kt = (y >> 3) * 8 + x;
    if (kt >= KTILES2) return;
    const int qbase = qt * 128, kbase = kt * 128;
    const int tid = threadIdx.x, lane = tid & 63, wave = tid >> 6;

    // stage both tiles: 32 chunks x 1KB each, linear lane order
    {
        const size_t qo = (size_t)qt * 16384 + (size_t)(wave * 8) * 512 + lane * 8;
        const size_t ko = (size_t)kt * 16384 + (size_t)(wave * 8) * 512 + lane * 8;
        #pragma unroll
        for (int c = 0; c < 8; ++c) {
            GLD16(Qf + qo + (size_t)c * 512, &Alds[(wave * 8 + c) * 512]);
            GLD16(Kf + ko + (size_t)c * 512, &Blds[(wave * 8 + c) * 512]);
        }
    }
    if (tid < 128) {
        const float qs = qsq_g[qbase + tid];
        qsq_s[tid] = qs;
        thr_s[tid] = tau_g[qbase + tid] + TSLACK - qs;
        ksq_s[tid] = ksq_g[kbase + tid];
    }
    __syncthreads();

    const int wr = wave >> 1, wc = wave & 1;   // 2x2 wave grid, 64q x 64k each
    f32x4 acc[4][4];
    #pragma unroll
    for (int i = 0; i < 4; ++i)
        #pragma unroll
        for (int j = 0; j < 4; ++j) acc[i][j] = (f32x4){0.f, 0.f, 0.f, 0.f};

    #pragma unroll
    for (int s = 0; s < 4; ++s) {
        f16x8 af[4], bfr[4];
        #pragma unroll
        for (int i = 0; i < 4; ++i)
            af[i] = *(const f16x8*)&Alds[((wr * 4 + i) * 4 + s) * 512 + lane * 8];
        #pragma unroll
        for (int j = 0; j < 4; ++j)
            bfr[j] = *(const f16x8*)&Blds[((wc * 4 + j) * 4 + s) * 512 + lane * 8];
        #pragma unroll
        for (int i = 0; i < 4; ++i)
            #pragma unroll
            for (int j = 0; j < 4; ++j)
                acc[i][j] = __builtin_amdgcn_mfma_f32_16x16x32_f16(af[i], bfr[j], acc[i][j], 0, 0, 0);
    }

    // epilogue: dist = qsq + (ksq - 2*dot); append candidates below tau+slack
    const int col  = lane & 15;
    const int rowb = (lane >> 4) * 4;
    #pragma unroll
    for (int i = 0; i < 4; ++i) {
        #pragma unroll
        for (int j = 0; j < 4; ++j) {
            #pragma unroll
            for (int r = 0; r < 4; ++r) {
                const int ql = wr * 64 + i * 16 + rowb + r;
                const int kl = wc * 64 + j * 16 + col;
                const float mm = fmaf(-2.f, acc[i][j][r], ksq_s[kl]);
                if (mm < thr_s[ql]) {
                    const float dist = qsq_s[ql] + mm;
                    const int qg = qbase + ql;
                    const unsigned p = atomicAdd(&cnt[qg], 1u);
                    if ((int)p < cap)
                        cand[(size_t)qg * cap + p] =
                            make_float2(dist, __uint_as_float((unsigned)(kbase + kl)));
                }
            }
        }
    }
}

// ================================================================ select: approx window -> exact fp32 recompute -> IDW
__global__ void select_exact_kernel(const float2* __restrict__ cand, const unsigned int* __restrict__ cnt,
                                    const float* __restrict__ keys, const float* __restrict__ qry,
                                    const float* __restrict__ ksq_g, const float* __restrict__ qsq_g,
                                    const float* __restrict__ values, float* __restrict__ out, int cap) {
    __shared__ float Qs[DIM];
    __shared__ ull keyarr[CAP_NEW];
    __shared__ int keep[256];
    __shared__ ull ex[256];
    __shared__ ull sel[KNN];
    __shared__ float vv[KNN];
    __shared__ unsigned int cnt_s, ns;
    const int q = blockIdx.x, tid = threadIdx.x;

    if (tid < 32) ((float4*)Qs)[tid] = ((const float4*)(qry + (size_t)q * DIM))[tid];
    const int c = min((int)cnt[q], cap);
    for (int i = tid; i < c; i += 256) {
        const float2 f = cand[(size_t)q * cap + i];
        keyarr[i] = ((ull)__float_as_uint(f.x) << 32) | __float_as_uint(f.y);
    }
    __syncthreads();

    const int ksel = min(KNN, c);
    if (ksel == 0) { if (tid == 0) out[q] = 0.f; return; }

    // 1) ksel-th smallest approx key
    ull lo = 0ull, hi = ~0ull;
    while (hi - lo > 1ull) {
        const ull mid = lo + ((hi - lo) >> 1);
        if (tid == 0) cnt_s = 0;
        __syncthreads();
        unsigned int lc = 0;
        for (int i = tid; i < c; i += 256) lc += (keyarr[i] < mid) ? 1u : 0u;
        #pragma unroll
        for (int off = 32; off; off >>= 1) lc += __shfl_down(lc, off);
        if ((tid & 63) == 0) atomicAdd(&cnt_s, lc);
        __syncthreads();
        if (cnt_s >= (unsigned)ksel) hi = mid; else lo = mid;
        __syncthreads();
    }
    const float a50 = __uint_as_float((unsigned)(lo >> 32));
    const unsigned cutb = __float_as_uint(a50 + MARGIN);

    // 2) keep approx <= a50 + margin
    if (tid == 0) ns = 0;
    __syncthreads();
    for (int i = tid; i < c; i += 256) {
        if ((unsigned)(keyarr[i] >> 32) <= cutb) {
            const unsigned p = atomicAdd(&ns, 1u);
            if (p < 256u) keep[p] = (int)(keyarr[i] & 0xFFFFFFFFull);
        }
    }
    __syncthreads();
    const int m = min((int)ns, 256);

    // 3) exact fp32 distances for kept window
    const float qsq = qsq_g[q];
    for (int j = tid; j < m; j += 256) {
        const int kidx = keep[j];
        const float* kr = keys + (size_t)kidx * DIM;
        float dot = 0.f;
        for (int d = 0; d < DIM; d++) dot = fmaf(Qs[d], kr[d], dot);
        const float mm = fmaf(-2.f, dot, ksq_g[kidx]);
        const float dist = qsq + mm;
        ex[j] = ((ull)__float_as_uint(dist) << 32) | (unsigned)kidx;
    }
    __syncthreads();

    const int kex = min(KNN, m);
    // 4) exact kex-th smallest among kept
    lo = 0ull; hi = ~0ull;
    while (hi - lo > 1ull) {
        const ull mid = lo + ((hi - lo) >> 1);
        if (tid == 0) cnt_s = 0;
        __syncthreads();
        unsigned int lc = 0;
        for (int i = tid; i < m; i += 256) lc += (ex[i] < mid) ? 1u : 0u;
        #pragma unroll
        for (int off = 32; off; off >>= 1) lc += __shfl_down(lc, off);
        if ((tid & 63) == 0) atomicAdd(&cnt_s, lc);
        __syncthreads();
        if (cnt_s >= (unsigned)kex) hi = mid; else lo = mid;
        __syncthreads();
    }
    const ull thr2 = lo;

    if (tid == 0) ns = 0;
    __syncthreads();
    for (int i = tid; i < m; i += 256) {
        if (ex[i] <= thr2) {
            const unsigned p = atomicAdd(&ns, 1u);
            if (p < (unsigned)KNN) sel[p] = ex[i];
        }
    }
    __syncthreads();

    if (tid == 0) {  // deterministic: insertion sort ascending (dist, idx)
        for (int a = 1; a < kex; a++) {
            const ull xk = sel[a];
            int b = a - 1;
            while (b >= 0 && sel[b] > xk) { sel[b + 1] = sel[b]; b--; }
            sel[b + 1] = xk;
        }
    }
    __syncthreads();
    if (tid < kex) vv[tid] = values[(unsigned)(sel[tid] & 0xFFFFFFFFull)];
    __syncthreads();

    if (tid == 0) {
        const float d0 = fmaxf(__uint_as_float((unsigned)(sel[0] >> 32)), 0.f);
        float res;
        if (d0 == 0.f) {
            res = vv[0];
        } else {
            float S = 0.f;
            for (int i = 0; i < kex; i++) {
                const float di = fmaxf(__uint_as_float((unsigned)(sel[i] >> 32)), 0.f);
                S += 1.f / (di + DELTA);
            }
            float o = 0.f;
            for (int i = 0; i < kex; i++) {
                const float di = fmaxf(__uint_as_float((unsigned)(sel[i] >> 32)), 0.f);
                const float w = 1.f / (di + DELTA);
                o += (w / S) * vv[i];
            }
            res = o;
        }
        out[q] = res;
    }
}

// ================================================================ launcher
extern "C" void kernel_launch(void* const* d_in, const int* in_sizes, int n_in,
                              void* d_out, int out_size, void* d_ws, size_t ws_size,
                              hipStream_t stream) {
    const float* qry    = (const float*)d_in[0];   // [1024,128]
    const float* keys   = (const float*)d_in[1];   // [200000,128]
    const float* values = (const float*)d_in[2];   // [200000,1]
    float* out = (float*)d_out;
    char* ws = (char*)d_ws;

    const size_t KF_OFF   = 0;
    const size_t QF_OFF   = KF_OFF + (size_t)NKP * DIM * 2;       // 51,216,384
    const size_t KSQ_OFF  = QF_OFF + (size_t)N_Q * DIM * 2;
    const size_t QSQ_OFF  = KSQ_OFF + (size_t)NKP * 4;
    const size_t TAU_OFF  = QSQ_OFF + 4096;
    const size_t CNT_OFF  = TAU_OFF + 4096;
    const size_t CAND_OFF = CNT_OFF + 4096;

    ushort* Kf  = (ushort*)(ws + KF_OFF);
    ushort* Qf  = (ushort*)(ws + QF_OFF);
    float*  ksq = (float*)(ws + KSQ_OFF);
    float*  qsq = (float*)(ws + QSQ_OFF);
    float*  tau = (float*)(ws + TAU_OFF);
    unsigned int* cnt = (unsigned int*)(ws + CNT_OFF);
    float2* cand = (float2*)(ws + CAND_OFF);

    const int PREP_BLOCKS = (int)((NKP / 16 + N_Q / 16 + 3) / 4);   // 3142

    hipLaunchKernelGGL(zero_cnt_kernel, dim3(4), dim3(256), 0, stream, cnt);
    hipLaunchKernelGGL(prep_kernel, dim3(PREP_BLOCKS), dim3(256), 0, stream,
                       qry, keys, Kf, Qf, ksq, qsq);
    hipLaunchKernelGGL(tau_kernel, dim3(N_Q), dim3(256), 0, stream, qry, keys, tau, SAMPLE_RANK);
    hipLaunchKernelGGL(mfma_filter_kernel, dim3(GRID_FILTER), dim3(256), 0, stream,
                       Qf, Kf, ksq, qsq, tau, cnt, cand, CAP_NEW);
    hipLaunchKernelGGL(select_exact_kernel, dim3(N_Q), dim3(256), 0, stream,
                       cand, cnt, keys, qry, ksq, qsq, values, out, CAP_NEW);
}